// Round 6
// baseline (1130.863 us; speedup 1.0000x reference)
//
#include <hip/hip_runtime.h>
#include <math.h>

// Problem constants
#define NLAYER 4
#define NH     8
#define CDIM   512
#define HS     64
#define VOCAB  32000
#define BB     2
#define TT     2048
#define MROWS  (BB*TT)     // 4096
#define QKVW   (3*CDIM)    // 1536
#define NHEADS (BB*NH)     // 16
#define NSPLIT 4

typedef __attribute__((ext_vector_type(8))) short bf16x8;
typedef __attribute__((ext_vector_type(4))) float f32x4;

__device__ __forceinline__ unsigned short f2bf(float f) {
    unsigned int u = __float_as_uint(f);
    u += 0x7FFF + ((u >> 16) & 1);   // RNE
    return (unsigned short)(u >> 16);
}

#define GLOAD16(g, l) __builtin_amdgcn_global_load_lds( \
    (const __attribute__((address_space(1))) void*)(g), \
    (__attribute__((address_space(3))) void*)(l), 16, 0, 0)

// ---------------------------------------------------------------------------
// bf16 MFMA GEMM, m97 structure: 128x128 tile, BK=64, 4 waves, 16x16x32 MFMA.
// C[M,N] = A[M,K] @ Bt[N,K]^T. flags: 1=bias, 2=relu, 4=residual-add (f32).
// MSWIZ: launch grid (mtiles, ntiles); m-tile fastest within XCD-chunk so each
// XCD reuses one B-panel from its L2 while A stays L2/L3-resident.
// ---------------------------------------------------------------------------
template<int FLAGS, bool OUTBF, bool MSWIZ>
__global__ __launch_bounds__(256) void mfma_gemm(
    const unsigned short* __restrict__ A, int lda,
    const unsigned short* __restrict__ Bt, int ldb,
    const float* __restrict__ bias,
    void* __restrict__ Cout, int ldc,
    const float* __restrict__ resid,
    int K)
{
    __shared__ unsigned short As[128*64];
    __shared__ unsigned short Bs[128*64];
    const int tid = threadIdx.x;
    const int w = tid >> 6, l = tid & 63;
    const int wr = w >> 1, wc = w & 1;
    long m0, n0;
    if (MSWIZ) {
        const int mt = gridDim.x;
        const int flat = blockIdx.y * mt + blockIdx.x;
        const int cpx = (mt * gridDim.y) >> 3;       // blocks per XCD (nb%8==0)
        const int swz = (flat & 7) * cpx + (flat >> 3);
        m0 = (long)(swz % mt) * 128;
        n0 = (long)(swz / mt) * 128;
    } else {
        m0 = (long)blockIdx.y * 128;
        n0 = (long)blockIdx.x * 128;
    }
    const int srow = l >> 3;
    const int scol = (l & 7) << 3;
    const unsigned short* Ab = A + m0*lda;
    const unsigned short* Bb = Bt + n0*ldb;
    const int fr = l & 15;
    const int fk = (l >> 4) << 3;

    f32x4 acc[4][4];
    #pragma unroll
    for (int m = 0; m < 4; m++)
        #pragma unroll
        for (int n = 0; n < 4; n++) acc[m][n] = (f32x4)0.0f;

    for (int k0 = 0; k0 < K; k0 += 64) {
        __syncthreads();
        #pragma unroll
        for (int i = 0; i < 4; i++) {
            int seg = w*4 + i;
            GLOAD16(Ab + (long)(seg*8 + srow)*lda + k0 + scol, As + seg*512);
            GLOAD16(Bb + (long)(seg*8 + srow)*ldb + k0 + scol, Bs + seg*512);
        }
        __syncthreads();
        #pragma unroll
        for (int kk = 0; kk < 2; kk++) {
            bf16x8 af[4], bf[4];
            #pragma unroll
            for (int m = 0; m < 4; m++)
                af[m] = *(const bf16x8*)&As[(wr*64 + m*16 + fr)*64 + kk*32 + fk];
            #pragma unroll
            for (int n = 0; n < 4; n++)
                bf[n] = *(const bf16x8*)&Bs[(wc*64 + n*16 + fr)*64 + kk*32 + fk];
            #pragma unroll
            for (int m = 0; m < 4; m++)
                #pragma unroll
                for (int n = 0; n < 4; n++)
                    acc[m][n] = __builtin_amdgcn_mfma_f32_16x16x32_bf16(
                        af[m], bf[n], acc[m][n], 0, 0, 0);
        }
    }

    const int rg = (l >> 4) << 2;
    #pragma unroll
    for (int n = 0; n < 4; n++) {
        long gn = n0 + wc*64 + n*16 + fr;
        float bv = (FLAGS & 1) ? bias[gn] : 0.f;
        #pragma unroll
        for (int m = 0; m < 4; m++) {
            #pragma unroll
            for (int r = 0; r < 4; r++) {
                long gm = m0 + wr*64 + m*16 + rg + r;
                float val = acc[m][n][r] + bv;
                if (FLAGS & 2) val = fmaxf(val, 0.f);
                if (FLAGS & 4) val += resid[gm*ldc + gn];
                if (OUTBF) ((unsigned short*)Cout)[gm*ldc + gn] = f2bf(val);
                else       ((float*)Cout)[gm*ldc + gn] = val;
            }
        }
    }
}

// ---------------------------------------------------------------------------
// QKV GEMM: same core, scatter epilogue -> qh/kh [head][t][d], vt [head][d][t]
// ---------------------------------------------------------------------------
__global__ __launch_bounds__(256) void mfma_gemm_qkv(
    const unsigned short* __restrict__ A,
    const unsigned short* __restrict__ Bt,
    unsigned short* __restrict__ qh,
    unsigned short* __restrict__ kh,
    unsigned short* __restrict__ vt)
{
    __shared__ unsigned short As[128*64];
    __shared__ unsigned short Bs[128*64];
    const int tid = threadIdx.x;
    const int w = tid >> 6, l = tid & 63;
    const int wr = w >> 1, wc = w & 1;
    const long m0 = (long)blockIdx.y * 128;
    const long n0 = (long)blockIdx.x * 128;
    const int srow = l >> 3;
    const int scol = (l & 7) << 3;
    const unsigned short* Ab = A + m0*CDIM;
    const unsigned short* Bb = Bt + n0*CDIM;
    const int fr = l & 15;
    const int fk = (l >> 4) << 3;

    f32x4 acc[4][4];
    #pragma unroll
    for (int m = 0; m < 4; m++)
        #pragma unroll
        for (int n = 0; n < 4; n++) acc[m][n] = (f32x4)0.0f;

    for (int k0 = 0; k0 < CDIM; k0 += 64) {
        __syncthreads();
        #pragma unroll
        for (int i = 0; i < 4; i++) {
            int seg = w*4 + i;
            GLOAD16(Ab + (long)(seg*8 + srow)*CDIM + k0 + scol, As + seg*512);
            GLOAD16(Bb + (long)(seg*8 + srow)*CDIM + k0 + scol, Bs + seg*512);
        }
        __syncthreads();
        #pragma unroll
        for (int kk = 0; kk < 2; kk++) {
            bf16x8 af[4], bf[4];
            #pragma unroll
            for (int m = 0; m < 4; m++)
                af[m] = *(const bf16x8*)&As[(wr*64 + m*16 + fr)*64 + kk*32 + fk];
            #pragma unroll
            for (int n = 0; n < 4; n++)
                bf[n] = *(const bf16x8*)&Bs[(wc*64 + n*16 + fr)*64 + kk*32 + fk];
            #pragma unroll
            for (int m = 0; m < 4; m++)
                #pragma unroll
                for (int n = 0; n < 4; n++)
                    acc[m][n] = __builtin_amdgcn_mfma_f32_16x16x32_bf16(
                        af[m], bf[n], acc[m][n], 0, 0, 0);
        }
    }

    const int rg = (l >> 4) << 2;
    #pragma unroll
    for (int n = 0; n < 4; n++) {
        int gn = (int)(n0 + wc*64 + n*16 + fr);
        int which = gn >> 9, hh = (gn >> 6) & 7, d = gn & 63;
        #pragma unroll
        for (int m = 0; m < 4; m++) {
            #pragma unroll
            for (int r = 0; r < 4; r++) {
                int gm = (int)(m0 + wr*64 + m*16 + rg + r);
                int b = gm >> 11, t = gm & (TT-1);
                int head = b*NH + hh;
                unsigned short val = f2bf(acc[m][n][r]);
                if (which == 0)      qh[((long)head*TT + t)*HS + d] = val;
                else if (which == 1) kh[((long)head*TT + t)*HS + d] = val;
                else                 vt[((long)head*HS + d)*TT + t] = val;
            }
        }
    }
}

// ---------------------------------------------------------------------------
// Barrier-free MFMA flash attention, strided split-KV=4.
// grid (TT/128, NHEADS, NSPLIT), 4 independent waves x 32 q-rows each.
// K/V fragments loaded directly from global (K/V L2-fit; no LDS staging,
// no __syncthreads). Wave-private LDS only for the P C->A transpose.
// Writes UNNORMALIZED partial O (f32) + per-row (m,l).
// ---------------------------------------------------------------------------
__global__ __launch_bounds__(256) void attn_part(
    const unsigned short* __restrict__ qh,
    const unsigned short* __restrict__ kh,
    const unsigned short* __restrict__ vt,
    float* __restrict__ oP, float* __restrict__ ml)
{
    __shared__ unsigned short Ps[4][32*72];
    const int tid = threadIdx.x;
    const int w = tid >> 6, l = tid & 63;
    const int fr = l & 15, g = l >> 4;
    const int head = blockIdx.y;
    const int sp = blockIdx.z;
    const int qw = (blockIdx.x*4 + w) * 32;      // wave-private 32 rows
    const unsigned short* Qb = qh + (long)head*TT*HS;
    const unsigned short* Kb = kh + (long)head*TT*HS;
    const unsigned short* Vb = vt + (long)head*HS*TT;

    // Q fragments (A-layout), loaded once
    bf16x8 aq[2][2];
    #pragma unroll
    for (int mt = 0; mt < 2; mt++)
        #pragma unroll
        for (int ks = 0; ks < 2; ks++)
            aq[mt][ks] = *(const bf16x8*)&Qb[(long)(qw + mt*16 + fr)*HS + ks*32 + g*8];

    f32x4 acc_o[2][4];
    float mrun[2][4], lsum[2][4];
    #pragma unroll
    for (int mt = 0; mt < 2; mt++) {
        #pragma unroll
        for (int r = 0; r < 4; r++) { mrun[mt][r] = -INFINITY; lsum[mt][r] = 0.f; }
        #pragma unroll
        for (int n = 0; n < 4; n++) acc_o[mt][n] = (f32x4)0.0f;
    }

    const int nc = qw/64 + 1;                    // causal chunk count for this wave
    for (int c = sp; c < nc; c += NSPLIT) {      // strided split assignment
        const int s0 = c*64;

        // --- K fragments (B-layout) straight from global/L2 ---
        bf16x8 bk[4][2];
        #pragma unroll
        for (int n = 0; n < 4; n++)
            #pragma unroll
            for (int ks = 0; ks < 2; ks++)
                bk[n][ks] = *(const bf16x8*)&Kb[(long)(s0 + n*16 + fr)*HS + ks*32 + g*8];

        f32x4 sc[2][4];
        #pragma unroll
        for (int mt = 0; mt < 2; mt++)
            #pragma unroll
            for (int n = 0; n < 4; n++) sc[mt][n] = (f32x4)0.0f;
        #pragma unroll
        for (int ks = 0; ks < 2; ks++)
            #pragma unroll
            for (int mt = 0; mt < 2; mt++)
                #pragma unroll
                for (int n = 0; n < 4; n++)
                    sc[mt][n] = __builtin_amdgcn_mfma_f32_16x16x32_bf16(
                        aq[mt][ks], bk[n][ks], sc[mt][n], 0, 0, 0);

        // --- causal mask: only the diagonal chunk is partially masked ---
        if (c == nc - 1) {
            #pragma unroll
            for (int mt = 0; mt < 2; mt++)
                #pragma unroll
                for (int r = 0; r < 4; r++) {
                    int q = qw + mt*16 + g*4 + r;
                    #pragma unroll
                    for (int n = 0; n < 4; n++)
                        if (s0 + n*16 + fr > q) sc[mt][n][r] = -INFINITY;
                }
        }

        // --- online softmax ---
        #pragma unroll
        for (int mt = 0; mt < 2; mt++) {
            #pragma unroll
            for (int r = 0; r < 4; r++) {
                float rmax = fmaxf(fmaxf(sc[mt][0][r], sc[mt][1][r]),
                                   fmaxf(sc[mt][2][r], sc[mt][3][r]));
                #pragma unroll
                for (int off = 8; off >= 1; off >>= 1)
                    rmax = fmaxf(rmax, __shfl_xor(rmax, off));
                float mnew = fmaxf(mrun[mt][r], rmax);   // finite for every kept chunk
                float scale = __expf(mrun[mt][r] - mnew);
                float ps = 0.f;
                #pragma unroll
                for (int n = 0; n < 4; n++) {
                    float p = __expf(sc[mt][n][r] - mnew);
                    sc[mt][n][r] = p;
                    ps += p;
                }
                #pragma unroll
                for (int off = 8; off >= 1; off >>= 1)
                    ps += __shfl_xor(ps, off);
                lsum[mt][r] = lsum[mt][r]*scale + ps;
                mrun[mt][r] = mnew;
                #pragma unroll
                for (int n = 0; n < 4; n++) acc_o[mt][n][r] *= scale;
            }
        }

        // --- P -> wave-private LDS (C-layout -> A-layout transpose) ---
        #pragma unroll
        for (int mt = 0; mt < 2; mt++)
            #pragma unroll
            for (int n = 0; n < 4; n++)
                #pragma unroll
                for (int r = 0; r < 4; r++)
                    Ps[w][(mt*16 + g*4 + r)*72 + n*16 + fr] = f2bf(sc[mt][n][r]);

        // --- O += P V  (V^T fragments straight from global/L2) ---
        bf16x8 ap[2][2], bv[4][2];
        #pragma unroll
        for (int mt = 0; mt < 2; mt++)
            #pragma unroll
            for (int ks = 0; ks < 2; ks++)
                ap[mt][ks] = *(const bf16x8*)&Ps[w][(mt*16 + fr)*72 + ks*32 + g*8];
        #pragma unroll
        for (int n = 0; n < 4; n++)
            #pragma unroll
            for (int ks = 0; ks < 2; ks++)
                bv[n][ks] = *(const bf16x8*)&Vb[(long)(n*16 + fr)*TT + s0 + ks*32 + g*8];
        #pragma unroll
        for (int ks = 0; ks < 2; ks++)
            #pragma unroll
            for (int mt = 0; mt < 2; mt++)
                #pragma unroll
                for (int n = 0; n < 4; n++)
                    acc_o[mt][n] = __builtin_amdgcn_mfma_f32_16x16x32_bf16(
                        ap[mt][ks], bv[n][ks], acc_o[mt][n], 0, 0, 0);
    }

    // store partials
    float* oB = oP + ((long)(head*NSPLIT + sp)*TT)*HS;
    float* mlB = ml + ((long)(head*NSPLIT + sp)*TT)*2;
    #pragma unroll
    for (int mt = 0; mt < 2; mt++) {
        #pragma unroll
        for (int n = 0; n < 4; n++)
            #pragma unroll
            for (int r = 0; r < 4; r++)
                oB[(long)(qw + mt*16 + g*4 + r)*HS + n*16 + fr] = acc_o[mt][n][r];
        if (fr == 0) {
            #pragma unroll
            for (int r = 0; r < 4; r++) {
                int t = qw + mt*16 + g*4 + r;
                mlB[t*2]     = mrun[mt][r];
                mlB[t*2 + 1] = lsum[mt][r];
            }
        }
    }
}

// combine 4 partials: att = sum_i O_i e^{m_i-M} / sum_i l_i e^{m_i-M}
__global__ __launch_bounds__(256) void attn_combine(
    const float* __restrict__ oP, const float* __restrict__ ml,
    unsigned short* __restrict__ att)
{
    const int gid = blockIdx.x*4 + (threadIdx.x >> 6);   // head*TT + t
    const int lane = threadIdx.x & 63;
    const int head = gid >> 11, t = gid & (TT-1);
    const int b = head >> 3, hh = head & 7;
    float m[NSPLIT], lv[NSPLIT];
    float M = -INFINITY;
    #pragma unroll
    for (int s = 0; s < NSPLIT; s++) {
        long i = (long)(head*NSPLIT + s)*TT + t;
        m[s] = ml[i*2]; lv[s] = ml[i*2+1];
        M = fmaxf(M, m[s]);
    }
    float L = 0.f, v = 0.f;
    #pragma unroll
    for (int s = 0; s < NSPLIT; s++) {
        float e = __expf(m[s] - M);                      // empty split: e^{-inf}=0
        L += lv[s]*e;
        v += oP[((long)(head*NSPLIT + s)*TT + t)*HS + lane]*e;
    }
    att[((long)b*TT + t)*CDIM + hh*HS + lane] = f2bf(v / L);
}

// ---------------------------------------------------------------------------
// Weight prep: f32 [R][Cn] -> bf16 [Cn][R], batched via grid.z
// ---------------------------------------------------------------------------
__global__ __launch_bounds__(256) void transpose_cast(
    const float* __restrict__ in, unsigned short* __restrict__ out,
    int R, int Cn, long in_z1, long in_z2, long out_z1, long out_z2, int z2n)
{
    const int z = blockIdx.z;
    const int z1 = z / z2n, z2 = z % z2n;
    const float* ip = in + (long)z1*in_z1 + (long)z2*in_z2;
    unsigned short* op = out + (long)z1*out_z1 + (long)z2*out_z2;
    __shared__ float tile[32][33];
    const int tx = threadIdx.x & 31, ty = threadIdx.x >> 5;
    const long r0 = (long)blockIdx.y*32, c0 = (long)blockIdx.x*32;
    #pragma unroll
    for (int i = 0; i < 4; i++)
        tile[ty + i*8][tx] = ip[(r0 + ty + i*8)*Cn + c0 + tx];
    __syncthreads();
    #pragma unroll
    for (int i = 0; i < 4; i++)
        op[(c0 + ty + i*8)*R + r0 + tx] = f2bf(tile[tx][ty + i*8]);
}

__global__ __launch_bounds__(256) void cast_kernel(
    const float* __restrict__ in, unsigned short* __restrict__ out, long n)
{
    long i = ((long)blockIdx.x*256 + threadIdx.x) * 4;
    if (i >= n) return;
    float4 v = *(const float4*)(in + i);
    ushort4 u = make_ushort4(f2bf(v.x), f2bf(v.y), f2bf(v.z), f2bf(v.w));
    *(ushort4*)(out + i) = u;
}

// ---------------------------------------------------------------------------
__global__ void embed_kernel(const int* __restrict__ idx,
                             const float* __restrict__ tok,
                             const float* __restrict__ pos,
                             float* __restrict__ x)
{
    const int r = blockIdx.x;
    const int t = r & (TT-1);
    const long tr = idx[r];
    const float* te = tok + tr*CDIM;
    const float* pe = pos + (long)t*CDIM;
    float* xo = x + (long)r*CDIM;
    for (int c = threadIdx.x; c < CDIM; c += blockDim.x)
        xo[c] = te[c] + pe[c];
}

// MODE 1: outp bf16 = LN(in).  MODE 2: outp f32 += LN(in).
// MODE 3: outp f32 += LN(in) AND outp2 bf16 = result.
template<int MODE>
__global__ __launch_bounds__(256) void ln_kernel(
    const float* __restrict__ in, const float* __restrict__ g,
    const float* __restrict__ bb, void* __restrict__ outp,
    void* __restrict__ outp2)
{
    const int wave = threadIdx.x >> 6;
    const int lane = threadIdx.x & 63;
    const long r = (long)blockIdx.x*4 + wave;
    const float* xr = in + r*CDIM;
    float vals[8];
    float s = 0.f;
    #pragma unroll
    for (int i = 0; i < 8; i++) { vals[i] = xr[lane + i*64]; s += vals[i]; }
    #pragma unroll
    for (int o = 32; o >= 1; o >>= 1) s += __shfl_xor(s, o);
    const float mean = s * (1.f/CDIM);
    float vs = 0.f;
    #pragma unroll
    for (int i = 0; i < 8; i++) { float d = vals[i]-mean; vs += d*d; }
    #pragma unroll
    for (int o = 32; o >= 1; o >>= 1) vs += __shfl_xor(vs, o);
    const float rstd = rsqrtf(vs*(1.f/CDIM) + 1e-5f);
    #pragma unroll
    for (int i = 0; i < 8; i++) {
        int c = lane + i*64;
        float nv = (vals[i]-mean)*rstd*g[c] + bb[c];
        if (MODE == 1) {
            ((unsigned short*)outp)[r*CDIM + c] = f2bf(nv);
        } else {
            float s2 = ((float*)outp)[r*CDIM + c] + nv;
            ((float*)outp)[r*CDIM + c] = s2;
            if (MODE == 3) ((unsigned short*)outp2)[r*CDIM + c] = f2bf(s2);
        }
    }
}

// ---------------------------------------------------------------------------
extern "C" void kernel_launch(void* const* d_in, const int* in_sizes, int n_in,
                              void* d_out, int out_size, void* d_ws, size_t ws_size,
                              hipStream_t stream)
{
    const int*   idx   = (const int*)  d_in[0];
    const float* tok   = (const float*)d_in[1];
    const float* pos   = (const float*)d_in[2];
    const float* ln1g  = (const float*)d_in[3];
    const float* ln1b  = (const float*)d_in[4];
    const float* wq    = (const float*)d_in[5];
    const float* wk    = (const float*)d_in[6];
    const float* wv    = (const float*)d_in[7];
    const float* projw = (const float*)d_in[8];
    const float* projb = (const float*)d_in[9];
    const float* ln2g  = (const float*)d_in[10];
    const float* ln2b  = (const float*)d_in[11];
    const float* ffw1  = (const float*)d_in[12];
    const float* ffb1  = (const float*)d_in[13];
    const float* ffw2  = (const float*)d_in[14];
    const float* ffb2  = (const float*)d_in[15];
    const float* flng  = (const float*)d_in[16];
    const float* flnb  = (const float*)d_in[17];
    const float* lmw   = (const float*)d_in[18];
    const float* lmb   = (const float*)d_in[19];
    float* out = (float*)d_out;

    // ---- workspace layout (~91.5 MB) ----
    char* wp = (char*)d_ws;
    float* x  = (float*)wp;           wp += (size_t)MROWS*CDIM*4;
    float* ff = (float*)wp;           wp += (size_t)MROWS*CDIM*4;
    unsigned short* h     = (unsigned short*)wp; wp += (size_t)MROWS*CDIM*2;
    unsigned short* lmt   = (unsigned short*)wp; wp += (size_t)VOCAB*CDIM*2;
    unsigned short* ff1t  = (unsigned short*)wp; wp += (size_t)NLAYER*4*CDIM*CDIM*2;
    unsigned short* ff2t  = (unsigned short*)wp; wp += (size_t)NLAYER*4*CDIM*CDIM*2;
    unsigned short* qkvt  = (unsigned short*)wp; wp += (size_t)NLAYER*QKVW*CDIM*2;
    unsigned short* projc = (unsigned short*)wp; wp += (size_t)NLAYER*CDIM*CDIM*2;
    unsigned short* qh    = (unsigned short*)wp; wp += (size_t)NHEADS*TT*HS*2;
    unsigned short* kh    = (unsigned short*)wp; wp += (size_t)NHEADS*TT*HS*2;
    unsigned short* vt    = (unsigned short*)wp; wp += (size_t)NHEADS*TT*HS*2;

    // ---- scratch in d_out (dead before LM-head GEMM fully overwrites it) ----
    unsigned short* f1  = (unsigned short*)d_out;          // [MROWS][2048] bf16, 16.8MB
    unsigned short* att = f1 + (size_t)MROWS*4*CDIM;       // [MROWS][512] bf16,  4.2MB
    float* oP = (float*)(att + (size_t)MROWS*CDIM);        // [NHEADS*4][TT][HS] f32, 33.5MB
    float* ml = oP + (size_t)NHEADS*NSPLIT*TT*HS;          // [NHEADS*4][TT][2]  f32,  1MB

    // ---- weight prep (bf16, [N][K] panels) ----
    transpose_cast<<<dim3(VOCAB/32, CDIM/32, 1), 256, 0, stream>>>(
        lmw, lmt, CDIM, VOCAB, 0, 0, 0, 0, 1);
    transpose_cast<<<dim3(4*CDIM/32, CDIM/32, NLAYER), 256, 0, stream>>>(
        ffw1, ff1t, CDIM, 4*CDIM, (long)CDIM*4*CDIM, 0, (long)4*CDIM*CDIM, 0, 1);
    transpose_cast<<<dim3(CDIM/32, 4*CDIM/32, NLAYER), 256, 0, stream>>>(
        ffw2, ff2t, 4*CDIM, CDIM, (long)4*CDIM*CDIM, 0, (long)CDIM*4*CDIM, 0, 1);
    {
        const size_t QBLK = (size_t)CDIM * CDIM;   // 262144 elements
        transpose_cast<<<dim3(HS/32, CDIM/32, NLAYER*NH), 256, 0, stream>>>(
            wq, qkvt,            CDIM, HS,
            (long)NH*CDIM*HS, (long)CDIM*HS, (long)QKVW*CDIM, (long)HS*CDIM, NH);
        transpose_cast<<<dim3(HS/32, CDIM/32, NLAYER*NH), 256, 0, stream>>>(
            wk, qkvt + QBLK,     CDIM, HS,
            (long)NH*CDIM*HS, (long)CDIM*HS, (long)QKVW*CDIM, (long)HS*CDIM, NH);
        transpose_cast<<<dim3(HS/32, CDIM/32, NLAYER*NH), 256, 0, stream>>>(
            wv, qkvt + 2*QBLK,   CDIM, HS,
            (long)NH*CDIM*HS, (long)CDIM*HS, (long)QKVW*CDIM, (long)HS*CDIM, NH);
    }
    cast_kernel<<<(NLAYER*CDIM*CDIM/4 + 255)/256, 256, 0, stream>>>(
        projw, projc, (long)NLAYER*CDIM*CDIM);

    embed_kernel<<<MROWS, 256, 0, stream>>>(idx, tok, pos, x);

    for (int l = 0; l < NLAYER; l++) {
        const unsigned short* qkvt_l = qkvt + (size_t)l*QKVW*CDIM;
        const unsigned short* projc_l = projc + (size_t)l*CDIM*CDIM;
        const unsigned short* ff1t_l = ff1t + (size_t)l*4*CDIM*CDIM;
        const unsigned short* ff2t_l = ff2t + (size_t)l*4*CDIM*CDIM;

        ln_kernel<1><<<MROWS/4, 256, 0, stream>>>(x, ln1g + l*CDIM, ln1b + l*CDIM, h, nullptr);

        mfma_gemm_qkv<<<dim3(QKVW/128, MROWS/128), 256, 0, stream>>>(
            h, qkvt_l, qh, kh, vt);

        attn_part<<<dim3(TT/128, NHEADS, NSPLIT), 256, 0, stream>>>(qh, kh, vt, oP, ml);
        attn_combine<<<dim3(NHEADS*TT/4), 256, 0, stream>>>(oP, ml, att);

        mfma_gemm<5,false,false><<<dim3(CDIM/128, MROWS/128), 256, 0, stream>>>(
            att, CDIM, projc_l, CDIM, projb + l*CDIM, x, CDIM, x, CDIM);

        ln_kernel<1><<<MROWS/4, 256, 0, stream>>>(x, ln2g + l*CDIM, ln2b + l*CDIM, h, nullptr);

        mfma_gemm<3,true,false><<<dim3(4*CDIM/128, MROWS/128), 256, 0, stream>>>(
            h, CDIM, ff1t_l, CDIM, ffb1 + (size_t)l*4*CDIM, f1, 4*CDIM, nullptr, CDIM);

        mfma_gemm<1,false,false><<<dim3(CDIM/128, MROWS/128), 256, 0, stream>>>(
            f1, 4*CDIM, ff2t_l, 4*CDIM, ffb2 + l*CDIM, ff, CDIM, nullptr, 4*CDIM);

        if (l == NLAYER-1)
            ln_kernel<3><<<MROWS/4, 256, 0, stream>>>(ff, flng + l*CDIM, flnb + l*CDIM, x, h);
        else
            ln_kernel<2><<<MROWS/4, 256, 0, stream>>>(ff, flng + l*CDIM, flnb + l*CDIM, x, nullptr);
    }

    // LM head: out = x @ lm_w + lm_b   (m-tile-fastest + XCD-chunk swizzle)
    mfma_gemm<1,false,true><<<dim3(MROWS/128, VOCAB/128), 256, 0, stream>>>(
        h, CDIM, lmt, CDIM, lmb, out, VOCAB, nullptr, CDIM);
}

// Round 7
// 935.927 us; speedup vs baseline: 1.2083x; 1.2083x over previous
//
#include <hip/hip_runtime.h>
#include <math.h>

// Problem constants
#define NLAYER 4
#define NH     8
#define CDIM   512
#define HS     64
#define VOCAB  32000
#define BB     2
#define TT     2048
#define MROWS  (BB*TT)     // 4096
#define QKVW   (3*CDIM)    // 1536
#define NHEADS (BB*NH)     // 16
#define ASPLIT 2

typedef __attribute__((ext_vector_type(8))) short bf16x8;
typedef __attribute__((ext_vector_type(4))) float f32x4;

__device__ __forceinline__ unsigned short f2bf(float f) {
    unsigned int u = __float_as_uint(f);
    u += 0x7FFF + ((u >> 16) & 1);   // RNE
    return (unsigned short)(u >> 16);
}

#define GLOAD16(g, l) __builtin_amdgcn_global_load_lds( \
    (const __attribute__((address_space(1))) void*)(g), \
    (__attribute__((address_space(3))) void*)(l), 16, 0, 0)

// swizzled LDS element offset: row-major [*][64] bf16 tile, 16B chunk xor'd by row&7
#define SWZ(row, chunk) (((row)*64) + ((((chunk) ^ ((row)&7)))*8))

// ---------------------------------------------------------------------------
// bf16 MFMA GEMM: 128x128 tile, BK=64, 4 waves, 16x16x32 MFMA.
// Double-buffered LDS (1 barrier/K-step), T2 XOR-swizzled tiles.
// C[M,N] = A[M,K] @ Bt[N,K]^T. FLAGS: 1=bias, 2=relu, 4=resid-add, 8=nontemporal C.
// ---------------------------------------------------------------------------
template<int FLAGS, bool OUTBF, bool MSWIZ>
__global__ __launch_bounds__(256) void mfma_gemm(
    const unsigned short* __restrict__ A, int lda,
    const unsigned short* __restrict__ Bt, int ldb,
    const float* __restrict__ bias,
    void* __restrict__ Cout, int ldc,
    const float* __restrict__ resid,
    int K)
{
    __shared__ unsigned short As[2][128*64];
    __shared__ unsigned short Bs[2][128*64];
    const int tid = threadIdx.x;
    const int w = tid >> 6, l = tid & 63;
    const int wr = w >> 1, wc = w & 1;
    long m0, n0;
    if (MSWIZ) {
        const int mt = gridDim.x;
        const int flat = blockIdx.y * mt + blockIdx.x;
        const int cpx = (mt * gridDim.y) >> 3;       // blocks per XCD (nb%8==0)
        const int swz = (flat & 7) * cpx + (flat >> 3);
        m0 = (long)(swz % mt) * 128;
        n0 = (long)(swz / mt) * 128;
    } else {
        m0 = (long)blockIdx.y * 128;
        n0 = (long)blockIdx.x * 128;
    }
    const int srow = l >> 3;                          // row within 8-row segment
    const int scol = ((l & 7) ^ (srow & 7)) << 3;     // inverse-swizzled src col (elems)
    const unsigned short* Ab = A + m0*lda;
    const unsigned short* Bb = Bt + n0*ldb;
    const int fr = l & 15;
    const int g  = l >> 4;

    f32x4 acc[4][4];
    #pragma unroll
    for (int m = 0; m < 4; m++)
        #pragma unroll
        for (int n = 0; n < 4; n++) acc[m][n] = (f32x4)0.0f;

    auto stage = [&](int k0, int buf) {
        #pragma unroll
        for (int i = 0; i < 4; i++) {
            int seg = w*4 + i;                        // 16 segments of 8 rows
            GLOAD16(Ab + (long)(seg*8 + srow)*lda + k0 + scol, &As[buf][seg*512]);
            GLOAD16(Bb + (long)(seg*8 + srow)*ldb + k0 + scol, &Bs[buf][seg*512]);
        }
    };

    const int nk = K >> 6;
    stage(0, 0);
    for (int ks = 0; ks < nk; ks++) {
        const int buf = ks & 1;
        __syncthreads();                              // stage(ks) done; prev readers done
        if (ks + 1 < nk) stage((ks+1) << 6, buf ^ 1); // prefetch under compute
        #pragma unroll
        for (int kk = 0; kk < 2; kk++) {
            bf16x8 af[4], bf[4];
            #pragma unroll
            for (int m = 0; m < 4; m++) {
                int row = wr*64 + m*16 + fr;
                af[m] = *(const bf16x8*)&As[buf][SWZ(row, kk*4 + g)];
            }
            #pragma unroll
            for (int n = 0; n < 4; n++) {
                int row = wc*64 + n*16 + fr;
                bf[n] = *(const bf16x8*)&Bs[buf][SWZ(row, kk*4 + g)];
            }
            #pragma unroll
            for (int m = 0; m < 4; m++)
                #pragma unroll
                for (int n = 0; n < 4; n++)
                    acc[m][n] = __builtin_amdgcn_mfma_f32_16x16x32_bf16(
                        af[m], bf[n], acc[m][n], 0, 0, 0);
        }
    }

    // epilogue: C/D layout col=lane&15, row=(lane>>4)*4+reg
    const int rg = g << 2;
    #pragma unroll
    for (int n = 0; n < 4; n++) {
        long gn = n0 + wc*64 + n*16 + fr;
        float bv = (FLAGS & 1) ? bias[gn] : 0.f;
        #pragma unroll
        for (int m = 0; m < 4; m++) {
            #pragma unroll
            for (int r = 0; r < 4; r++) {
                long gm = m0 + wr*64 + m*16 + rg + r;
                float val = acc[m][n][r] + bv;
                if (FLAGS & 2) val = fmaxf(val, 0.f);
                if (FLAGS & 4) val += resid[gm*ldc + gn];
                if (OUTBF) {
                    ((unsigned short*)Cout)[gm*ldc + gn] = f2bf(val);
                } else if (FLAGS & 8) {
                    __builtin_nontemporal_store(val, &((float*)Cout)[gm*ldc + gn]);
                } else {
                    ((float*)Cout)[gm*ldc + gn] = val;
                }
            }
        }
    }
}

// ---------------------------------------------------------------------------
// QKV GEMM: same core, scatter epilogue -> qh/kh [head][t][d], vt [head][d][t]
// ---------------------------------------------------------------------------
__global__ __launch_bounds__(256) void mfma_gemm_qkv(
    const unsigned short* __restrict__ A,
    const unsigned short* __restrict__ Bt,
    unsigned short* __restrict__ qh,
    unsigned short* __restrict__ kh,
    unsigned short* __restrict__ vt)
{
    __shared__ unsigned short As[2][128*64];
    __shared__ unsigned short Bs[2][128*64];
    const int tid = threadIdx.x;
    const int w = tid >> 6, l = tid & 63;
    const int wr = w >> 1, wc = w & 1;
    const long m0 = (long)blockIdx.y * 128;
    const long n0 = (long)blockIdx.x * 128;
    const int srow = l >> 3;
    const int scol = ((l & 7) ^ (srow & 7)) << 3;
    const unsigned short* Ab = A + m0*CDIM;
    const unsigned short* Bb = Bt + n0*CDIM;
    const int fr = l & 15;
    const int g  = l >> 4;

    f32x4 acc[4][4];
    #pragma unroll
    for (int m = 0; m < 4; m++)
        #pragma unroll
        for (int n = 0; n < 4; n++) acc[m][n] = (f32x4)0.0f;

    auto stage = [&](int k0, int buf) {
        #pragma unroll
        for (int i = 0; i < 4; i++) {
            int seg = w*4 + i;
            GLOAD16(Ab + (long)(seg*8 + srow)*CDIM + k0 + scol, &As[buf][seg*512]);
            GLOAD16(Bb + (long)(seg*8 + srow)*CDIM + k0 + scol, &Bs[buf][seg*512]);
        }
    };

    const int nk = CDIM >> 6;
    stage(0, 0);
    for (int ks = 0; ks < nk; ks++) {
        const int buf = ks & 1;
        __syncthreads();
        if (ks + 1 < nk) stage((ks+1) << 6, buf ^ 1);
        #pragma unroll
        for (int kk = 0; kk < 2; kk++) {
            bf16x8 af[4], bf[4];
            #pragma unroll
            for (int m = 0; m < 4; m++) {
                int row = wr*64 + m*16 + fr;
                af[m] = *(const bf16x8*)&As[buf][SWZ(row, kk*4 + g)];
            }
            #pragma unroll
            for (int n = 0; n < 4; n++) {
                int row = wc*64 + n*16 + fr;
                bf[n] = *(const bf16x8*)&Bs[buf][SWZ(row, kk*4 + g)];
            }
            #pragma unroll
            for (int m = 0; m < 4; m++)
                #pragma unroll
                for (int n = 0; n < 4; n++)
                    acc[m][n] = __builtin_amdgcn_mfma_f32_16x16x32_bf16(
                        af[m], bf[n], acc[m][n], 0, 0, 0);
        }
    }

    const int rg = g << 2;
    #pragma unroll
    for (int n = 0; n < 4; n++) {
        int gn = (int)(n0 + wc*64 + n*16 + fr);
        int which = gn >> 9, hh = (gn >> 6) & 7, d = gn & 63;
        #pragma unroll
        for (int m = 0; m < 4; m++) {
            #pragma unroll
            for (int r = 0; r < 4; r++) {
                int gm = (int)(m0 + wr*64 + m*16 + rg + r);
                int b = gm >> 11, t = gm & (TT-1);
                int head = b*NH + hh;
                unsigned short val = f2bf(acc[m][n][r]);
                if (which == 0)      qh[((long)head*TT + t)*HS + d] = val;
                else if (which == 1) kh[((long)head*TT + t)*HS + d] = val;
                else                 vt[((long)head*HS + d)*TT + t] = val;
            }
        }
    }
}

// ---------------------------------------------------------------------------
// MFMA flash attention, split-KV=2 (round-5 structure). grid (TT/128, NHEADS, 2).
// 4 waves x 32 q-rows. K/V LDS-staged double-buffered, XOR-swizzled.
// Writes UNNORMALIZED partial O (f32) + per-row (m,l) for the combine pass.
// ---------------------------------------------------------------------------
__global__ __launch_bounds__(256) void attn_part(
    const unsigned short* __restrict__ qh,
    const unsigned short* __restrict__ kh,
    const unsigned short* __restrict__ vt,
    float* __restrict__ oP, float* __restrict__ ml)
{
    __shared__ unsigned short Ks[2][64*64];
    __shared__ unsigned short Vts[2][64*64];
    __shared__ unsigned short Ps[4][32*72];
    const int tid = threadIdx.x;
    const int w = tid >> 6, l = tid & 63;
    const int fr = l & 15, g = l >> 4;
    const int head = blockIdx.y;
    const int sp = blockIdx.z;
    const int x = blockIdx.x;
    const int qw = x*128 + w*32;
    const unsigned short* Qb = qh + (long)head*TT*HS;
    const unsigned short* Kb = kh + (long)head*TT*HS;
    const unsigned short* Vb = vt + (long)head*HS*TT;

    bf16x8 aq[2][2];
    #pragma unroll
    for (int mt = 0; mt < 2; mt++)
        #pragma unroll
        for (int ks = 0; ks < 2; ks++)
            aq[mt][ks] = *(const bf16x8*)&Qb[(long)(qw + mt*16 + fr)*HS + ks*32 + g*8];

    f32x4 acc_o[2][4];
    float mrun[2][4], lsum[2][4];
    #pragma unroll
    for (int mt = 0; mt < 2; mt++) {
        #pragma unroll
        for (int r = 0; r < 4; r++) { mrun[mt][r] = -INFINITY; lsum[mt][r] = 0.f; }
        #pragma unroll
        for (int n = 0; n < 4; n++) acc_o[mt][n] = (f32x4)0.0f;
    }

    const int cbeg = sp * (x + 1);
    const int cend = cbeg + (x + 1);
    const int srow = l >> 3;
    const int scol = ((l & 7) ^ (srow & 7)) << 3;

    auto stage = [&](int c) {
        int buf = c & 1;
        int s0_ = c*64;
        #pragma unroll
        for (int i = 0; i < 2; i++) {
            int rb = i*32 + w*8;
            GLOAD16(Kb + (long)(s0_ + rb + srow)*HS + scol, &Ks[buf][rb*64]);
            GLOAD16(Vb + (long)(rb + srow)*TT + s0_ + scol, &Vts[buf][rb*64]);
        }
    };

    stage(cbeg);
    for (int c = cbeg; c < cend; c++) {
        const int s0 = c*64;
        const int buf = c & 1;
        __syncthreads();
        if (c + 1 < cend) stage(c+1);
        if (s0 > qw + 31) continue;       // wave-uniform skip; staging already done

        bf16x8 bk[4][2];
        #pragma unroll
        for (int n = 0; n < 4; n++)
            #pragma unroll
            for (int ks = 0; ks < 2; ks++) {
                int row = n*16 + fr;
                bk[n][ks] = *(const bf16x8*)&Ks[buf][SWZ(row, ks*4 + g)];
            }
        f32x4 sc[2][4];
        #pragma unroll
        for (int mt = 0; mt < 2; mt++)
            #pragma unroll
            for (int n = 0; n < 4; n++) sc[mt][n] = (f32x4)0.0f;
        #pragma unroll
        for (int ks = 0; ks < 2; ks++)
            #pragma unroll
            for (int mt = 0; mt < 2; mt++)
                #pragma unroll
                for (int n = 0; n < 4; n++)
                    sc[mt][n] = __builtin_amdgcn_mfma_f32_16x16x32_bf16(
                        aq[mt][ks], bk[n][ks], sc[mt][n], 0, 0, 0);

        #pragma unroll
        for (int mt = 0; mt < 2; mt++) {
            #pragma unroll
            for (int r = 0; r < 4; r++) {
                int q = qw + mt*16 + g*4 + r;
                float rmax = -INFINITY;
                #pragma unroll
                for (int n = 0; n < 4; n++) {
                    float v = sc[mt][n][r];
                    v = (s0 + n*16 + fr <= q) ? v : -INFINITY;
                    sc[mt][n][r] = v;
                    rmax = fmaxf(rmax, v);
                }
                #pragma unroll
                for (int off = 8; off >= 1; off >>= 1)
                    rmax = fmaxf(rmax, __shfl_xor(rmax, off));
                float mnew = fmaxf(mrun[mt][r], rmax);
                float scale = __expf(mrun[mt][r] - mnew);
                float ps = 0.f;
                #pragma unroll
                for (int n = 0; n < 4; n++) {
                    float p = __expf(sc[mt][n][r] - mnew);
                    sc[mt][n][r] = p;
                    ps += p;
                }
                #pragma unroll
                for (int off = 8; off >= 1; off >>= 1)
                    ps += __shfl_xor(ps, off);
                lsum[mt][r] = lsum[mt][r]*scale + ps;
                mrun[mt][r] = mnew;
                #pragma unroll
                for (int n = 0; n < 4; n++) acc_o[mt][n][r] *= scale;
            }
        }

        #pragma unroll
        for (int mt = 0; mt < 2; mt++)
            #pragma unroll
            for (int n = 0; n < 4; n++)
                #pragma unroll
                for (int r = 0; r < 4; r++)
                    Ps[w][(mt*16 + g*4 + r)*72 + n*16 + fr] = f2bf(sc[mt][n][r]);

        bf16x8 ap[2][2], bv[4][2];
        #pragma unroll
        for (int mt = 0; mt < 2; mt++)
            #pragma unroll
            for (int ks = 0; ks < 2; ks++)
                ap[mt][ks] = *(const bf16x8*)&Ps[w][(mt*16 + fr)*72 + ks*32 + g*8];
        #pragma unroll
        for (int n = 0; n < 4; n++)
            #pragma unroll
            for (int ks = 0; ks < 2; ks++) {
                int row = n*16 + fr;
                bv[n][ks] = *(const bf16x8*)&Vts[buf][SWZ(row, ks*4 + g)];
            }
        #pragma unroll
        for (int ks = 0; ks < 2; ks++)
            #pragma unroll
            for (int mt = 0; mt < 2; mt++)
                #pragma unroll
                for (int n = 0; n < 4; n++)
                    acc_o[mt][n] = __builtin_amdgcn_mfma_f32_16x16x32_bf16(
                        ap[mt][ks], bv[n][ks], acc_o[mt][n], 0, 0, 0);
    }

    float* oB = oP + ((long)(head*ASPLIT + sp)*TT)*HS;
    float* mlB = ml + ((long)(head*ASPLIT + sp)*TT)*2;
    #pragma unroll
    for (int mt = 0; mt < 2; mt++) {
        #pragma unroll
        for (int n = 0; n < 4; n++)
            #pragma unroll
            for (int r = 0; r < 4; r++)
                oB[(long)(qw + mt*16 + g*4 + r)*HS + n*16 + fr] = acc_o[mt][n][r];
        if (fr == 0) {
            #pragma unroll
            for (int r = 0; r < 4; r++) {
                int t = qw + mt*16 + g*4 + r;
                mlB[t*2]     = mrun[mt][r];
                mlB[t*2 + 1] = lsum[mt][r];
            }
        }
    }
}

// combine ASPLIT partials
__global__ __launch_bounds__(256) void attn_combine(
    const float* __restrict__ oP, const float* __restrict__ ml,
    unsigned short* __restrict__ att)
{
    const int gid = blockIdx.x*4 + (threadIdx.x >> 6);   // head*TT + t
    const int lane = threadIdx.x & 63;
    const int head = gid >> 11, t = gid & (TT-1);
    const int b = head >> 3, hh = head & 7;
    float m[ASPLIT], lv[ASPLIT];
    float M = -INFINITY;
    #pragma unroll
    for (int s = 0; s < ASPLIT; s++) {
        long i = (long)(head*ASPLIT + s)*TT + t;
        m[s] = ml[i*2]; lv[s] = ml[i*2+1];
        M = fmaxf(M, m[s]);
    }
    float L = 0.f, v = 0.f;
    #pragma unroll
    for (int s = 0; s < ASPLIT; s++) {
        float e = __expf(m[s] - M);                      // empty split: e^{-inf}=0
        L += lv[s]*e;
        v += oP[((long)(head*ASPLIT + s)*TT + t)*HS + lane]*e;
    }
    att[((long)b*TT + t)*CDIM + hh*HS + lane] = f2bf(v / L);
}

// ---------------------------------------------------------------------------
// Weight prep: f32 [R][Cn] -> bf16 [Cn][R], batched via grid.z
// ---------------------------------------------------------------------------
__global__ __launch_bounds__(256) void transpose_cast(
    const float* __restrict__ in, unsigned short* __restrict__ out,
    int R, int Cn, long in_z1, long in_z2, long out_z1, long out_z2, int z2n)
{
    const int z = blockIdx.z;
    const int z1 = z / z2n, z2 = z % z2n;
    const float* ip = in + (long)z1*in_z1 + (long)z2*in_z2;
    unsigned short* op = out + (long)z1*out_z1 + (long)z2*out_z2;
    __shared__ float tile[32][33];
    const int tx = threadIdx.x & 31, ty = threadIdx.x >> 5;
    const long r0 = (long)blockIdx.y*32, c0 = (long)blockIdx.x*32;
    #pragma unroll
    for (int i = 0; i < 4; i++)
        tile[ty + i*8][tx] = ip[(r0 + ty + i*8)*Cn + c0 + tx];
    __syncthreads();
    #pragma unroll
    for (int i = 0; i < 4; i++)
        op[(c0 + ty + i*8)*R + r0 + tx] = f2bf(tile[tx][ty + i*8]);
}

__global__ __launch_bounds__(256) void cast_kernel(
    const float* __restrict__ in, unsigned short* __restrict__ out, long n)
{
    long i = ((long)blockIdx.x*256 + threadIdx.x) * 4;
    if (i >= n) return;
    float4 v = *(const float4*)(in + i);
    ushort4 u = make_ushort4(f2bf(v.x), f2bf(v.y), f2bf(v.z), f2bf(v.w));
    *(ushort4*)(out + i) = u;
}

// ---------------------------------------------------------------------------
__global__ void embed_kernel(const int* __restrict__ idx,
                             const float* __restrict__ tok,
                             const float* __restrict__ pos,
                             float* __restrict__ x)
{
    const int r = blockIdx.x;
    const int t = r & (TT-1);
    const long tr = idx[r];
    const float* te = tok + tr*CDIM;
    const float* pe = pos + (long)t*CDIM;
    float* xo = x + (long)r*CDIM;
    for (int c = threadIdx.x; c < CDIM; c += blockDim.x)
        xo[c] = te[c] + pe[c];
}

// MODE 1: outp bf16 = LN(in).  MODE 2: outp f32 += LN(in).
// MODE 3: outp f32 += LN(in) AND outp2 bf16 = result.
template<int MODE>
__global__ __launch_bounds__(256) void ln_kernel(
    const float* __restrict__ in, const float* __restrict__ g,
    const float* __restrict__ bb, void* __restrict__ outp,
    void* __restrict__ outp2)
{
    const int wave = threadIdx.x >> 6;
    const int lane = threadIdx.x & 63;
    const long r = (long)blockIdx.x*4 + wave;
    const float* xr = in + r*CDIM;
    float vals[8];
    float s = 0.f;
    #pragma unroll
    for (int i = 0; i < 8; i++) { vals[i] = xr[lane + i*64]; s += vals[i]; }
    #pragma unroll
    for (int o = 32; o >= 1; o >>= 1) s += __shfl_xor(s, o);
    const float mean = s * (1.f/CDIM);
    float vs = 0.f;
    #pragma unroll
    for (int i = 0; i < 8; i++) { float d = vals[i]-mean; vs += d*d; }
    #pragma unroll
    for (int o = 32; o >= 1; o >>= 1) vs += __shfl_xor(vs, o);
    const float rstd = rsqrtf(vs*(1.f/CDIM) + 1e-5f);
    #pragma unroll
    for (int i = 0; i < 8; i++) {
        int c = lane + i*64;
        float nv = (vals[i]-mean)*rstd*g[c] + bb[c];
        if (MODE == 1) {
            ((unsigned short*)outp)[r*CDIM + c] = f2bf(nv);
        } else {
            float s2 = ((float*)outp)[r*CDIM + c] + nv;
            ((float*)outp)[r*CDIM + c] = s2;
            if (MODE == 3) ((unsigned short*)outp2)[r*CDIM + c] = f2bf(s2);
        }
    }
}

// ---------------------------------------------------------------------------
extern "C" void kernel_launch(void* const* d_in, const int* in_sizes, int n_in,
                              void* d_out, int out_size, void* d_ws, size_t ws_size,
                              hipStream_t stream)
{
    const int*   idx   = (const int*)  d_in[0];
    const float* tok   = (const float*)d_in[1];
    const float* pos   = (const float*)d_in[2];
    const float* ln1g  = (const float*)d_in[3];
    const float* ln1b  = (const float*)d_in[4];
    const float* wq    = (const float*)d_in[5];
    const float* wk    = (const float*)d_in[6];
    const float* wv    = (const float*)d_in[7];
    const float* projw = (const float*)d_in[8];
    const float* projb = (const float*)d_in[9];
    const float* ln2g  = (const float*)d_in[10];
    const float* ln2b  = (const float*)d_in[11];
    const float* ffw1  = (const float*)d_in[12];
    const float* ffb1  = (const float*)d_in[13];
    const float* ffw2  = (const float*)d_in[14];
    const float* ffb2  = (const float*)d_in[15];
    const float* flng  = (const float*)d_in[16];
    const float* flnb  = (const float*)d_in[17];
    const float* lmw   = (const float*)d_in[18];
    const float* lmb   = (const float*)d_in[19];
    float* out = (float*)d_out;

    // ---- workspace layout (~91.5 MB) ----
    char* wp = (char*)d_ws;
    float* x  = (float*)wp;           wp += (size_t)MROWS*CDIM*4;
    float* ff = (float*)wp;           wp += (size_t)MROWS*CDIM*4;
    unsigned short* h     = (unsigned short*)wp; wp += (size_t)MROWS*CDIM*2;
    unsigned short* lmt   = (unsigned short*)wp; wp += (size_t)VOCAB*CDIM*2;
    unsigned short* ff1t  = (unsigned short*)wp; wp += (size_t)NLAYER*4*CDIM*CDIM*2;
    unsigned short* ff2t  = (unsigned short*)wp; wp += (size_t)NLAYER*4*CDIM*CDIM*2;
    unsigned short* qkvt  = (unsigned short*)wp; wp += (size_t)NLAYER*QKVW*CDIM*2;
    unsigned short* projc = (unsigned short*)wp; wp += (size_t)NLAYER*CDIM*CDIM*2;
    unsigned short* qh    = (unsigned short*)wp; wp += (size_t)NHEADS*TT*HS*2;
    unsigned short* kh    = (unsigned short*)wp; wp += (size_t)NHEADS*TT*HS*2;
    unsigned short* vt    = (unsigned short*)wp; wp += (size_t)NHEADS*TT*HS*2;

    // ---- scratch in d_out (dead before LM-head GEMM fully overwrites it) ----
    unsigned short* f1  = (unsigned short*)d_out;          // [MROWS][2048] bf16, 16.8MB
    unsigned short* att = f1 + (size_t)MROWS*4*CDIM;       // [MROWS][512] bf16,  4.2MB
    float* oP = (float*)(att + (size_t)MROWS*CDIM);        // [NHEADS*2][TT][HS] f32, 16.8MB
    float* ml = oP + (size_t)NHEADS*ASPLIT*TT*HS;          // [NHEADS*2][TT][2]  f32, 0.5MB

    // ---- weight prep (bf16, [N][K] panels) ----
    transpose_cast<<<dim3(VOCAB/32, CDIM/32, 1), 256, 0, stream>>>(
        lmw, lmt, CDIM, VOCAB, 0, 0, 0, 0, 1);
    transpose_cast<<<dim3(4*CDIM/32, CDIM/32, NLAYER), 256, 0, stream>>>(
        ffw1, ff1t, CDIM, 4*CDIM, (long)CDIM*4*CDIM, 0, (long)4*CDIM*CDIM, 0, 1);
    transpose_cast<<<dim3(CDIM/32, 4*CDIM/32, NLAYER), 256, 0, stream>>>(
        ffw2, ff2t, 4*CDIM, CDIM, (long)4*CDIM*CDIM, 0, (long)CDIM*4*CDIM, 0, 1);
    {
        const size_t QBLK = (size_t)CDIM * CDIM;   // 262144 elements
        transpose_cast<<<dim3(HS/32, CDIM/32, NLAYER*NH), 256, 0, stream>>>(
            wq, qkvt,            CDIM, HS,
            (long)NH*CDIM*HS, (long)CDIM*HS, (long)QKVW*CDIM, (long)HS*CDIM, NH);
        transpose_cast<<<dim3(HS/32, CDIM/32, NLAYER*NH), 256, 0, stream>>>(
            wk, qkvt + QBLK,     CDIM, HS,
            (long)NH*CDIM*HS, (long)CDIM*HS, (long)QKVW*CDIM, (long)HS*CDIM, NH);
        transpose_cast<<<dim3(HS/32, CDIM/32, NLAYER*NH), 256, 0, stream>>>(
            wv, qkvt + 2*QBLK,   CDIM, HS,
            (long)NH*CDIM*HS, (long)CDIM*HS, (long)QKVW*CDIM, (long)HS*CDIM, NH);
    }
    cast_kernel<<<(NLAYER*CDIM*CDIM/4 + 255)/256, 256, 0, stream>>>(
        projw, projc, (long)NLAYER*CDIM*CDIM);

    embed_kernel<<<MROWS, 256, 0, stream>>>(idx, tok, pos, x);

    for (int l = 0; l < NLAYER; l++) {
        const unsigned short* qkvt_l = qkvt + (size_t)l*QKVW*CDIM;
        const unsigned short* projc_l = projc + (size_t)l*CDIM*CDIM;
        const unsigned short* ff1t_l = ff1t + (size_t)l*4*CDIM*CDIM;
        const unsigned short* ff2t_l = ff2t + (size_t)l*4*CDIM*CDIM;

        ln_kernel<1><<<MROWS/4, 256, 0, stream>>>(x, ln1g + l*CDIM, ln1b + l*CDIM, h, nullptr);

        mfma_gemm_qkv<<<dim3(QKVW/128, MROWS/128), 256, 0, stream>>>(
            h, qkvt_l, qh, kh, vt);

        attn_part<<<dim3(TT/128, NHEADS, ASPLIT), 256, 0, stream>>>(qh, kh, vt, oP, ml);
        attn_combine<<<dim3(NHEADS*TT/4), 256, 0, stream>>>(oP, ml, att);

        mfma_gemm<5,false,false><<<dim3(CDIM/128, MROWS/128), 256, 0, stream>>>(
            att, CDIM, projc_l, CDIM, projb + l*CDIM, x, CDIM, x, CDIM);

        ln_kernel<1><<<MROWS/4, 256, 0, stream>>>(x, ln2g + l*CDIM, ln2b + l*CDIM, h, nullptr);

        mfma_gemm<3,true,false><<<dim3(4*CDIM/128, MROWS/128), 256, 0, stream>>>(
            h, CDIM, ff1t_l, CDIM, ffb1 + (size_t)l*4*CDIM, f1, 4*CDIM, nullptr, CDIM);

        mfma_gemm<1,false,false><<<dim3(CDIM/128, MROWS/128), 256, 0, stream>>>(
            f1, 4*CDIM, ff2t_l, 4*CDIM, ffb2 + l*CDIM, ff, CDIM, nullptr, 4*CDIM);

        if (l == NLAYER-1)
            ln_kernel<3><<<MROWS/4, 256, 0, stream>>>(ff, flng + l*CDIM, flnb + l*CDIM, x, h);
        else
            ln_kernel<2><<<MROWS/4, 256, 0, stream>>>(ff, flng + l*CDIM, flnb + l*CDIM, x, nullptr);
    }

    // LM head: out = x @ lm_w + lm_b  (MSWIZ + nontemporal C stores)
    mfma_gemm<9,false,true><<<dim3(MROWS/128, VOCAB/128), 256, 0, stream>>>(
        h, CDIM, lmt, CDIM, lmb, out, VOCAB, nullptr, CDIM);
}